// Round 2
// baseline (1885.093 us; speedup 1.0000x reference)
//
#include <hip/hip_runtime.h>

// TreecrfLossSRL: inside algorithm (logsumexp semiring), B=64, N=256.
// Two CYK charts per batch (ob / allv) -> scalar (logz - marg).sum()/denom.
//
// Dual chart layout per chart c:
//   Astart[i][u-1] : value of span starting at i, width u   (row stride 256)
//   Bend  [j][v-1] : value of span ending   at j, width v   (row stride 256)
// For entry (i,w): left stream  = Astart[i][q],     q = 0..w-2 (ascending)
//                  right stream = Bend[i+w-1][T-1-q]          (descending)
// Both contiguous -> dwordx4-mergeable / line-friendly.

#define NN 256
#define BATCH 64
#define NEGV -1000000000.0f
#define NEGB -1e30f
#define CHART_F (2 * NN * NN)             /* floats per chart (both layouts) */
#define NCHART (2 * BATCH)                /* 128 charts */
#define RES_OFF ((size_t)NCHART * CHART_F)
#define LEN_OFF (RES_OFF + NCHART)

// score at span [i, j] for type t (0 = ob/constrained, 1 = allv)
__device__ __forceinline__ float score_at(const float* __restrict__ logits,
                                          const int* __restrict__ spans_ind,
                                          const void* __restrict__ span_mask,
                                          int isb, int t, int b, int i, int j) {
    size_t sidx = ((size_t)b * NN + i) * NN + j;
    float l0 = logits[2 * sidx];
    float l1 = logits[2 * sidx + 1];
    if (t) {
        float mx = fmaxf(l0, l1), mn = fminf(l0, l1);
        return mx + log1pf(__expf(mn - mx));
    } else {
        bool sind = (spans_ind[sidx] == 2);
        bool sm = isb ? (((const unsigned char*)span_mask)[sidx] != 0)
                      : (((const int*)span_mask)[sidx] != 0);
        float s0 = (sm || sind)  ? NEGV : l0;
        float s1 = (sm || !sind) ? NEGV : l1;
        float mx = fmaxf(s0, s1), mn = fminf(s0, s1);
        return mx + log1pf(__expf(mn - mx));
    }
}

__global__ __launch_bounds__(1024) void cyk_kernel(
    const float* __restrict__ logits,     // [B,N,N,2] f32
    const int* __restrict__ spans_ind,    // [B,N,N] i32
    const void* __restrict__ maskspan,    // [B,N,N] bool (byte or i32)
    const void* __restrict__ span_mask,   // [B,N,N] bool
    float* __restrict__ ws) {
    const int c = blockIdx.x;
    const int b = c >> 1;
    const int t = c & 1;
    float* __restrict__ Ast = ws + (size_t)c * CHART_F;
    float* __restrict__ Ben = Ast + NN * NN;
    const int tid = threadIdx.x;

    __shared__ int s_len;
    __shared__ int s_isb;
    if (tid == 0) {
        s_len = 0;
        unsigned probe = *(const unsigned*)maskspan;
        s_isb = (probe > 1u) ? 1 : 0;  // byte-packed bools -> 0x01010101
    }
    __syncthreads();
    const int isb = s_isb;

    // lens[b] = sum_j maskspan[b,0,j]
    if (tid < NN) {
        size_t off = (size_t)b * NN * NN + tid;
        int v = isb ? (((const unsigned char*)maskspan)[off] ? 1 : 0)
                    : (((const int*)maskspan)[off] ? 1 : 0);
        atomicAdd(&s_len, v);
    }

    // width-1 init: A(i,1) = D(i,1) = score[i,i]; write both layouts
    if (tid < NN) {
        float v = score_at(logits, spans_ind, span_mask, isb, t, b, tid, tid);
        Ast[(tid << 8) + 0] = v;
        Ben[(tid << 8) + 0] = v;
    }
    __syncthreads();

    for (int w = 2; w <= NN; ++w) {
        const int T = w - 1;          // number of split points
        const int E = NN - w + 1;     // valid entries at this width
        // P = pow2 sub-lanes per entry, P*E <= 1024, P <= 64, P >= 4
        int P = 1024 / E;
        int sh;
        if (P >= 64) { P = 64; sh = 6; }
        else { sh = 31 - __clz(P); P = 1 << sh; }
        const int g = tid >> sh;
        const int s = tid & (P - 1);

        if (g < E) {
            const float* __restrict__ Arow = Ast + (g << 8);
            const float* __restrict__ Brow = Ben + ((g + T) << 8);
            // contiguous 4-aligned chunk of q = u-1 in [0, T)
            const int per = (((T + P - 1) / P) + 3) & ~3;
            const int q0 = s * per;
            const int q1 = min(q0 + per, T);
            float m = NEGB, sum = 0.0f;
            for (int q = q0; q < q1; q += 4) {
                // unconditional loads (rows padded to 256; ws poison is inert)
                float l0 = Arow[q];
                float l1 = Arow[q + 1];
                float l2 = Arow[q + 2];
                float l3 = Arow[q + 3];
                float r0 = Brow[T - 1 - q];
                float r1 = Brow[T - 2 - q];
                float r2 = Brow[T - 3 - q];
                float r3 = Brow[T - 4 - q];
                float t0 = l0 + r0;
                float t1 = (q + 1 < q1) ? (l1 + r1) : NEGB;
                float t2 = (q + 2 < q1) ? (l2 + r2) : NEGB;
                float t3 = (q + 3 < q1) ? (l3 + r3) : NEGB;
                float gm = fmaxf(fmaxf(t0, t1), fmaxf(t2, t3));
                float nm = fmaxf(m, gm);
                sum = sum * __expf(m - nm)
                    + __expf(t0 - nm) + __expf(t1 - nm)
                    + __expf(t2 - nm) + __expf(t3 - nm);
                m = nm;
            }
            // wave-local (m,sum) butterfly across P contiguous sub-lanes
            for (int d = P >> 1; d > 0; d >>= 1) {
                float m2 = __shfl_xor(m, d);
                float s2 = __shfl_xor(sum, d);
                float mn = fmaxf(m, m2);
                sum = sum * __expf(m - mn) + s2 * __expf(m2 - mn);
                m = mn;
            }
            if (s == 0) {
                float dsc = score_at(logits, spans_ind, span_mask, isb, t, b,
                                     g, g + T);
                float val = dsc + m + __logf(sum);
                Ast[(g << 8) + (w - 1)] = val;
                Ben[((g + T) << 8) + (w - 1)] = val;
            }
        }
        __syncthreads();
    }

    if (tid == 0) {
        int len = s_len;
        float r = (len >= 1) ? Ast[0 + (len - 1)] : NEGV;  // span [0, len-1]
        ws[RES_OFF + c] = r;
        if (t == 0) ws[LEN_OFF + b] = (float)len;
    }
}

__global__ __launch_bounds__(64) void finish_kernel(const float* __restrict__ ws,
                                                    float* __restrict__ out) {
    int b = threadIdx.x;  // 0..63
    float diff = ws[RES_OFF + 2 * b + 1] - ws[RES_OFF + 2 * b];
    float len  = ws[LEN_OFF + b];
    for (int d = 32; d > 0; d >>= 1) {
        diff += __shfl_xor(diff, d);
        len  += __shfl_xor(len, d);
    }
    if (b == 0) out[0] = diff / len;
}

extern "C" void kernel_launch(void* const* d_in, const int* in_sizes, int n_in,
                              void* d_out, int out_size, void* d_ws, size_t ws_size,
                              hipStream_t stream) {
    const float* logits    = (const float*)d_in[0];
    const int*   spans_ind = (const int*)d_in[1];
    const void*  maskspan  = d_in[2];
    const void*  span_mask = d_in[3];
    float* ws = (float*)d_ws;

    hipLaunchKernelGGL(cyk_kernel, dim3(NCHART), dim3(1024), 0, stream,
                       logits, spans_ind, maskspan, span_mask, ws);
    hipLaunchKernelGGL(finish_kernel, dim3(1), dim3(64), 0, stream,
                       ws, (float*)d_out);
}

// Round 3
// 1014.102 us; speedup vs baseline: 1.8589x; 1.8589x over previous
//
#include <hip/hip_runtime.h>

// TreecrfLossSRL: inside algorithm (logsumexp semiring), B=64, N=256.
// Two CYK charts per batch (ob / allv) -> scalar (logz - marg).sum()/denom.
//
// Chart stored TWICE, both triangular-packed, values scaled by log2(e):
//   start-major (rows padded to x4 floats) in LDS (133 KB, opt-in)  -> left
//     stream A[i][1..w-1] is contiguous ascending, aligned ds_read_b128.
//   end-major in global ws (32896 fl/chart, 16.8 MB total, L2-resident)
//     -> right stream A[i+u][w-u] = End[i+w-1][w-u] contiguous descending.
// Base-2 domain: exp() -> native v_exp_f32 (exp2), log -> __log2f.

#define NN 256
#define BATCH 64
#define NCHART (2 * BATCH)
#define NEGV -1000000000.0f
#define NEGB -1.0e30f
#define K2f 1.4426950408889634f   /* log2(e) */
#define LN2f 0.6931471805599453f
#define ENDTRI (NN * (NN + 1) / 2)          /* 32896 floats per end-major chart */
#define PADTRI 33280                         /* start-major, rows padded to x4 */
#define GEND_OFF ((size_t)16)                /* pad so idx-underflow stays in ws */
#define FB_OFF (GEND_OFF + (size_t)NCHART * ENDTRI)
#define RES_OFF (FB_OFF + (size_t)NCHART * PADTRI)
#define LEN_OFF (RES_OFF + NCHART)

// padded start-major row offset: sum_{r<i} pad4(N-r)
__device__ __forceinline__ int rop(int i) {
    int r = i & 3;
    int extra = (r == 2) ? 1 : ((r == 3) ? 3 : 0);
    return (i << 8) - ((i * (i - 1)) >> 1) + 6 * (i >> 2) + extra;
}

// natural-log score at span [i, j] for type t (0 = ob/constrained, 1 = allv)
__device__ __forceinline__ float score_at(const float* __restrict__ logits,
                                          const int* __restrict__ spans_ind,
                                          const void* __restrict__ span_mask,
                                          int isb, int t, int b, int i, int j) {
    size_t sidx = ((size_t)b * NN + i) * NN + j;
    float l0 = logits[2 * sidx];
    float l1 = logits[2 * sidx + 1];
    if (t) {
        float mx = fmaxf(l0, l1), mn = fminf(l0, l1);
        return mx + log1pf(__expf(mn - mx));
    } else {
        bool sind = (spans_ind[sidx] == 2);
        bool sm = isb ? (((const unsigned char*)span_mask)[sidx] != 0)
                      : (((const int*)span_mask)[sidx] != 0);
        float s0 = (sm || sind)  ? NEGV : l0;
        float s1 = (sm || !sind) ? NEGV : l1;
        float mx = fmaxf(s0, s1), mn = fminf(s0, s1);
        return mx + log1pf(__expf(mn - mx));
    }
}

template <bool USE_LDS>
__global__ __launch_bounds__(1024) void cyk_kernel(
    const float* __restrict__ logits,     // [B,N,N,2] f32
    const int* __restrict__ spans_ind,    // [B,N,N] i32
    const void* __restrict__ maskspan,    // [B,N,N] bool (byte or i32)
    const void* __restrict__ span_mask,   // [B,N,N] bool
    float* __restrict__ ws) {
    extern __shared__ float lds[];
    const int c = blockIdx.x;
    const int b = c >> 1;
    const int t = c & 1;
    const int tid = threadIdx.x;
    float* __restrict__ Gend = ws + GEND_OFF + (size_t)c * ENDTRI;
    float* __restrict__ L =
        USE_LDS ? lds : (ws + FB_OFF + (size_t)c * PADTRI);

    __shared__ int s_len;
    __shared__ int s_isb;
    if (tid == 0) {
        s_len = 0;
        unsigned probe = *(const unsigned*)maskspan;
        s_isb = (probe > 1u) ? 1 : 0;  // byte-packed bools -> 0x01010101
    }
    __syncthreads();
    const int isb = s_isb;

    // lens[b] = sum_j maskspan[b,0,j]
    if (tid < NN) {
        size_t off = (size_t)b * NN * NN + tid;
        int v = isb ? (((const unsigned char*)maskspan)[off] ? 1 : 0)
                    : (((const int*)maskspan)[off] ? 1 : 0);
        atomicAdd(&s_len, v);
    }

    // width-1 init (base-2 domain)
    if (tid < NN) {
        float v = K2f * score_at(logits, spans_ind, span_mask, isb, t, b, tid, tid);
        L[rop(tid)] = v;                            // start-major col 0
        Gend[((tid * (tid + 1)) >> 1)] = v;         // end-major row tid, col 0
    }
    __syncthreads();

    for (int w = 2; w <= NN; ++w) {
        const int T = w - 1;          // split points
        const int E = NN - w + 1;     // valid entries
        int P = 1024 / E;             // pow2 sub-lanes per entry, P*E <= 1024
        int sh;
        if (P >= 64) { P = 64; sh = 6; }
        else { sh = 31 - __clz(P); P = 1 << sh; }
        const int g = tid >> sh;
        const int s = tid & (P - 1);

        if (g < E) {
            const float* __restrict__ Lrow = L + rop(g);
            const int j = g + T;
            float* __restrict__ Gr = Gend + ((j * (j + 1)) >> 1);
            // prefetch D score early (only the writer lane needs it)
            float dsc = 0.0f;
            if (s == 0)
                dsc = K2f * score_at(logits, spans_ind, span_mask, isb, t, b, g, j);

            const int per = (((T + P - 1) >> sh) + 3) & ~3;
            const int q0 = s * per;
            const int q1 = min(q0 + per, T);
            float m = NEGB, sum = 0.0f;
            for (int q = q0; q < q1; q += 4) {
                float4 lv = *(const float4*)(Lrow + q);   // aligned (rows x4)
                const float* gp = Gr + (T - 4 - q);       // ascending 4 floats
                float g0 = gp[0], g1 = gp[1], g2 = gp[2], g3 = gp[3];
                float t0 = lv.x + g3;
                float t1 = (q + 1 < q1) ? (lv.y + g2) : NEGB;
                float t2 = (q + 2 < q1) ? (lv.z + g1) : NEGB;
                float t3 = (q + 3 < q1) ? (lv.w + g0) : NEGB;
                float gm = fmaxf(fmaxf(t0, t1), fmaxf(t2, t3));
                float nm = fmaxf(m, gm);
                sum = sum * exp2f(m - nm)
                    + exp2f(t0 - nm) + exp2f(t1 - nm)
                    + exp2f(t2 - nm) + exp2f(t3 - nm);
                m = nm;
            }
            // wave-local (m,sum) butterfly across P contiguous sub-lanes
            for (int d = P >> 1; d > 0; d >>= 1) {
                float m2 = __shfl_xor(m, d);
                float s2 = __shfl_xor(sum, d);
                float mn = fmaxf(m, m2);
                sum = sum * exp2f(m - mn) + s2 * exp2f(m2 - mn);
                m = mn;
            }
            if (s == 0) {
                float val = dsc + m + __log2f(sum);
                L[rop(g) + T] = val;   // start-major col w-1
                Gr[T] = val;           // end-major row j, col w-1
            }
        }
        __syncthreads();
    }

    if (tid == 0) {
        int len = s_len;
        float r = (len >= 1) ? (L[len - 1] * LN2f) : NEGV;  // row 0, col len-1
        ws[RES_OFF + c] = r;
        if (t == 0) ws[LEN_OFF + b] = (float)len;
    }
}

__global__ __launch_bounds__(64) void finish_kernel(const float* __restrict__ ws,
                                                    float* __restrict__ out) {
    int b = threadIdx.x;  // 0..63
    float diff = ws[RES_OFF + 2 * b + 1] - ws[RES_OFF + 2 * b];
    float len  = ws[LEN_OFF + b];
    for (int d = 32; d > 0; d >>= 1) {
        diff += __shfl_xor(diff, d);
        len  += __shfl_xor(len, d);
    }
    if (b == 0) out[0] = diff / len;
}

extern "C" void kernel_launch(void* const* d_in, const int* in_sizes, int n_in,
                              void* d_out, int out_size, void* d_ws, size_t ws_size,
                              hipStream_t stream) {
    const float* logits    = (const float*)d_in[0];
    const int*   spans_ind = (const int*)d_in[1];
    const void*  maskspan  = d_in[2];
    const void*  span_mask = d_in[3];
    float* ws = (float*)d_ws;

    const size_t shbytes = (size_t)PADTRI * sizeof(float);  // 133120 B
    hipError_t e = hipFuncSetAttribute(
        reinterpret_cast<const void*>(&cyk_kernel<true>),
        hipFuncAttributeMaxDynamicSharedMemorySize, (int)shbytes);
    if (e == hipSuccess) {
        hipLaunchKernelGGL(cyk_kernel<true>, dim3(NCHART), dim3(1024), shbytes,
                           stream, logits, spans_ind, maskspan, span_mask, ws);
    } else {
        hipLaunchKernelGGL(cyk_kernel<false>, dim3(NCHART), dim3(1024), 0,
                           stream, logits, spans_ind, maskspan, span_mask, ws);
    }
    hipLaunchKernelGGL(finish_kernel, dim3(1), dim3(64), 0, stream,
                       ws, (float*)d_out);
}